// Round 6
// baseline (489.300 us; speedup 1.0000x reference)
//
#include <hip/hip_runtime.h>
#include <hip/hip_bf16.h>
#include <math.h>

#define B_SZ 32
#define T_SZ 4096
#define A_SZ 128
#define E_SZ 512
#define D_SZ 1024
#define NCH  32          // t-chunks of 128

typedef __attribute__((ext_vector_type(8))) short short8;        // 8 bf16
typedef __attribute__((ext_vector_type(4))) float f32x4;
typedef __attribute__((ext_vector_type(4))) unsigned int u32x4;

union cvt8 { u32x4 u; short8 s; };

static __device__ __forceinline__ unsigned short f32_to_bf16_rne(float x) {
    unsigned int u = __float_as_uint(x);
    unsigned int r = (u + 0x7fffu + ((u >> 16) & 1u)) >> 16;
    return (unsigned short)r;
}
static __device__ __forceinline__ float bf16_to_f32(unsigned short h) {
    return __uint_as_float(((unsigned int)h) << 16);
}
static __device__ __forceinline__ float tanh_fast(float x) {
    float ax = fabsf(x);
    float e  = __expf(2.f * ax);
    float r  = 1.f - 2.f / (e + 1.f);
    return __builtin_copysignf(r, x);
}

// Truncation split of 8 f32 -> hi short8 + lo short8 (in-register, ~5 ops/elem)
static __device__ __forceinline__ void split8(const float4 x0, const float4 x1,
                                              short8& hi, short8& lo) {
    float xs[8] = {x0.x, x0.y, x0.z, x0.w, x1.x, x1.y, x1.z, x1.w};
    cvt8 h, l;
    #pragma unroll
    for (int j = 0; j < 4; ++j) {
        unsigned int u0 = __float_as_uint(xs[2 * j]);
        unsigned int u1 = __float_as_uint(xs[2 * j + 1]);
        h.u[j] = (u0 >> 16) | (u1 & 0xffff0000u);
        float lo0 = xs[2 * j]     - __uint_as_float(u0 & 0xffff0000u);
        float lo1 = xs[2 * j + 1] - __uint_as_float(u1 & 0xffff0000u);
        l.u[j] = (__float_as_uint(lo0) >> 16) | (__float_as_uint(lo1) & 0xffff0000u);
    }
    hi = h.s; lo = l.s;
}

// ---------------------------------------------------------------------------
// Prep: blocks 0..31  -> pq[b][a] = query[b]·Wq[:,a]
//       blocks 32..159 -> WmT hi/lo bf16 split: WmT[a][e] = split(Wm[e][a])
// ---------------------------------------------------------------------------
__global__ __launch_bounds__(256) void k_prep(const float* __restrict__ q,
                                              const float* __restrict__ Wq,
                                              const float* __restrict__ Wm,
                                              float* __restrict__ pq,
                                              unsigned short* __restrict__ WmTh,
                                              unsigned short* __restrict__ WmTl) {
    const int tid = threadIdx.x;
    if (blockIdx.x < 32) {
        const int b = blockIdx.x;
        __shared__ float ql[D_SZ];
        #pragma unroll
        for (int s = 0; s < D_SZ / 256; ++s)
            ql[s * 256 + tid] = q[b * D_SZ + s * 256 + tid];
        __syncthreads();
        if (tid < A_SZ) {
            const int a = tid;
            float acc = 0.f;
            #pragma unroll 8
            for (int d = 0; d < D_SZ; ++d)
                acc = fmaf(ql[d], Wq[d * A_SZ + a], acc);
            pq[b * A_SZ + a] = acc;
        }
    } else {
        const int a = blockIdx.x - 32;            // 0..127
        for (int e = tid; e < E_SZ; e += 256) {
            float x = Wm[(size_t)e * A_SZ + a];
            unsigned short h = f32_to_bf16_rne(x);
            float r = x - bf16_to_f32(h);
            unsigned short l = f32_to_bf16_rne(r);
            WmTh[(size_t)a * E_SZ + e] = h;
            WmTl[(size_t)a * E_SZ + e] = l;
        }
    }
}

// ---------------------------------------------------------------------------
// Fused scores + chunk softmax stats + chunk context partial.
// A (memory tile) loaded DIRECTLY into MFMA fragment registers from global
// (prefetched 1 chunk ahead), split hi/lo in-reg. B (WmT) double-buffered in
// LDS -> ONE barrier per chunk. K rotated per block to decorrelate HBM phases.
// grid: (NCH=32, B=32), block 256 (4 waves), 3 blocks/CU.
// ---------------------------------------------------------------------------
#define BST 40

__global__ __launch_bounds__(256, 3) void k_fused(
    const float* __restrict__ mem,
    const unsigned short* __restrict__ WmTh,
    const unsigned short* __restrict__ WmTl,
    const float* __restrict__ pq,
    const float* __restrict__ v,
    float* __restrict__ scores_raw,    // [B][T] raw scores (d_out align region)
    float* __restrict__ ctx_part,      // [NCH][B][E]
    float* __restrict__ mZ)            // [B][NCH][2] = {chunk max, chunk expsum}
{
    __shared__ unsigned short Bh[2][128 * BST];
    __shared__ unsigned short Bl[2][128 * BST];
    __shared__ float sc[128];
    __shared__ float wbuf[128];
    __shared__ float red[8];

    const int cb = blockIdx.x;
    const int b  = blockIdx.y;
    const int t0 = cb * 128;
    const int tid = threadIdx.x;
    const int w = tid >> 6;
    const int lane = tid & 63;
    const int l16 = lane & 15;
    const int lk = lane >> 4;   // 0..3
    const int rot = (cb + b) & 15;

    const float* memB = mem + ((size_t)b * T_SZ + t0) * E_SZ;

    // B staging coords: thread stages 2 (hi,lo) short8 pairs per chunk
    const int sa0 = tid >> 2;                 // 0..63  (a for s=0; +64 for s=1)
    const int ses = (tid & 3) << 3;           // 0,8,16,24

    // A fragment rows for this wave (m = 0,1)
    const int arow0 = w * 32 + l16;           // + m*16
    const int acol  = lk * 8;                 // + e0

    f32x4 acc[2][8];
    #pragma unroll
    for (int m = 0; m < 2; ++m)
        #pragma unroll
        for (int n = 0; n < 8; ++n)
            acc[m][n] = (f32x4){0.f, 0.f, 0.f, 0.f};

    // ---- prologue: stage B[rot] into buf0; load A[rot] frags into regs ----
    {
        const int e0 = rot * 32;
        #pragma unroll
        for (int s = 0; s < 2; ++s) {
            int a = sa0 + s * 64;
            *(short8*)&Bh[0][a * BST + ses] = *(const short8*)&WmTh[(size_t)a * E_SZ + e0 + ses];
            *(short8*)&Bl[0][a * BST + ses] = *(const short8*)&WmTl[(size_t)a * E_SZ + e0 + ses];
        }
    }
    float4 rA[2][2];
    {
        const int e0 = rot * 32;
        #pragma unroll
        for (int m = 0; m < 2; ++m) {
            const float* p = memB + (size_t)(arow0 + m * 16) * E_SZ + e0 + acol;
            rA[m][0] = *(const float4*)p;
            rA[m][1] = *(const float4*)(p + 4);
        }
    }
    __syncthreads();

    for (int c = 0; c < 16; ++c) {
        const int cur = c & 1;

        // issue B[c+1] loads first (so B ds_write waits counted vmcnt,
        // leaving the A prefetch below in flight), then A[c+1] loads.
        short8 rbh[2], rbl[2];
        float4 rn[2][2];
        if (c < 15) {
            const int en = ((c + 1 + rot) & 15) * 32;
            #pragma unroll
            for (int s = 0; s < 2; ++s) {
                int a = sa0 + s * 64;
                rbh[s] = *(const short8*)&WmTh[(size_t)a * E_SZ + en + ses];
                rbl[s] = *(const short8*)&WmTl[(size_t)a * E_SZ + en + ses];
            }
            #pragma unroll
            for (int m = 0; m < 2; ++m) {
                const float* p = memB + (size_t)(arow0 + m * 16) * E_SZ + en + acol;
                rn[m][0] = *(const float4*)p;
                rn[m][1] = *(const float4*)(p + 4);
            }
        }

        // convert current A regs -> hi/lo bf16 fragments (in-register)
        short8 ah[2], al[2];
        #pragma unroll
        for (int m = 0; m < 2; ++m)
            split8(rA[m][0], rA[m][1], ah[m], al[m]);

        // MFMA over 8 n-frags, B from LDS buf[cur]
        #pragma unroll
        for (int n = 0; n < 8; ++n) {
            int boff = (n * 16 + l16) * BST + lk * 8;
            short8 bh = *(const short8*)&Bh[cur][boff];
            short8 bl = *(const short8*)&Bl[cur][boff];
            acc[0][n] = __builtin_amdgcn_mfma_f32_16x16x32_bf16(ah[0], bh, acc[0][n], 0, 0, 0);
            acc[1][n] = __builtin_amdgcn_mfma_f32_16x16x32_bf16(ah[1], bh, acc[1][n], 0, 0, 0);
            acc[0][n] = __builtin_amdgcn_mfma_f32_16x16x32_bf16(al[0], bh, acc[0][n], 0, 0, 0);
            acc[1][n] = __builtin_amdgcn_mfma_f32_16x16x32_bf16(al[1], bh, acc[1][n], 0, 0, 0);
            acc[0][n] = __builtin_amdgcn_mfma_f32_16x16x32_bf16(ah[0], bl, acc[0][n], 0, 0, 0);
            acc[1][n] = __builtin_amdgcn_mfma_f32_16x16x32_bf16(ah[1], bl, acc[1][n], 0, 0, 0);
        }

        if (c < 15) {
            // B[c+1] regs -> LDS buf[cur^1]; carry A prefetch into rA
            #pragma unroll
            for (int s = 0; s < 2; ++s) {
                int a = sa0 + s * 64;
                *(short8*)&Bh[cur ^ 1][a * BST + ses] = rbh[s];
                *(short8*)&Bl[cur ^ 1][a * BST + ses] = rbl[s];
            }
            #pragma unroll
            for (int m = 0; m < 2; ++m) {
                rA[m][0] = rn[m][0];
                rA[m][1] = rn[m][1];
            }
        }
        __syncthreads();
    }

    // epilogue: tanh + v-dot, reduce over a-cols (l16 lanes)
    float pqr[8], vr[8];
    #pragma unroll
    for (int n = 0; n < 8; ++n) {
        pqr[n] = pq[b * A_SZ + n * 16 + l16];
        vr[n]  = v[n * 16 + l16];
    }
    #pragma unroll
    for (int m = 0; m < 2; ++m) {
        float part[4] = {0.f, 0.f, 0.f, 0.f};
        #pragma unroll
        for (int n = 0; n < 8; ++n)
            #pragma unroll
            for (int r = 0; r < 4; ++r)
                part[r] += tanh_fast(pqr[n] + acc[m][n][r]) * vr[n];
        #pragma unroll
        for (int r = 0; r < 4; ++r) {
            #pragma unroll
            for (int off = 1; off < 16; off <<= 1)
                part[r] += __shfl_xor(part[r], off);
        }
        if (l16 == 0) {
            const int tl = w * 32 + m * 16 + lk * 4;
            #pragma unroll
            for (int r = 0; r < 4; ++r)
                sc[tl + r] = part[r];
        }
    }
    __syncthreads();

    // chunk max over 128 scores
    float mv = sc[tid & 127];
    #pragma unroll
    for (int off = 1; off < 64; off <<= 1)
        mv = fmaxf(mv, __shfl_xor(mv, off));
    if (lane == 0) red[w] = mv;
    __syncthreads();
    const float Mc = fmaxf(fmaxf(red[0], red[1]), fmaxf(red[2], red[3]));

    // weights + chunk exp-sum; also dump raw scores
    float wv = 0.f;
    if (tid < 128) {
        wv = __expf(sc[tid] - Mc);
        wbuf[tid] = wv;
        scores_raw[(size_t)b * T_SZ + t0 + tid] = sc[tid];
    }
    float sv = wv;
    #pragma unroll
    for (int off = 1; off < 64; off <<= 1)
        sv += __shfl_xor(sv, off);
    if (lane == 0) red[4 + w] = sv;
    __syncthreads();
    if (tid == 0) {
        const float Zc = red[4] + red[5];
        mZ[(b * NCH + cb) * 2 + 0] = Mc;
        mZ[(b * NCH + cb) * 2 + 1] = Zc;
    }

    // chunk-local PV: ctx_c[e] = sum_t exp(s_t - Mc) * mem[t][e]  (L2/L3-hot)
    const int e2 = tid * 2;
    float2 a2 = make_float2(0.f, 0.f);
    #pragma unroll 8
    for (int t = 0; t < 128; ++t) {
        float2 mm = *(const float2*)(memB + (size_t)t * E_SZ + e2);
        const float wt = wbuf[t];
        a2.x = fmaf(wt, mm.x, a2.x);
        a2.y = fmaf(wt, mm.y, a2.y);
    }
    *(float2*)(ctx_part + ((size_t)cb * B_SZ + b) * E_SZ + e2) = a2;
}

// ---------------------------------------------------------------------------
// Combine: per b, merge 32 chunk partials; normalize ctx and alignments.
// grid: (32), block 256
// ---------------------------------------------------------------------------
__global__ __launch_bounds__(256) void k_combine(
    const float* __restrict__ ctx_part,
    const float* __restrict__ mZ,
    float* __restrict__ ctx,       // [B][E]
    float* __restrict__ align)     // [B][T] in-place raw -> normalized
{
    const int b = blockIdx.x;
    const int tid = threadIdx.x;
    float mc[NCH], zc[NCH], ec[NCH];
    float M = -1e30f;
    #pragma unroll
    for (int c = 0; c < NCH; ++c) {
        float2 p = *(const float2*)(mZ + (b * NCH + c) * 2);
        mc[c] = p.x; zc[c] = p.y;
        M = fmaxf(M, p.x);
    }
    float Z = 0.f;
    #pragma unroll
    for (int c = 0; c < NCH; ++c) {
        ec[c] = __expf(mc[c] - M);
        Z = fmaf(zc[c], ec[c], Z);
    }
    const float invZ = 1.f / Z;

    const int e2 = tid * 2;
    float2 a2 = make_float2(0.f, 0.f);
    #pragma unroll
    for (int c = 0; c < NCH; ++c) {
        float2 p = *(const float2*)(ctx_part + ((size_t)c * B_SZ + b) * E_SZ + e2);
        a2.x = fmaf(p.x, ec[c], a2.x);
        a2.y = fmaf(p.y, ec[c], a2.y);
    }
    float2 outv = make_float2(a2.x * invZ, a2.y * invZ);
    *(float2*)(ctx + (size_t)b * E_SZ + e2) = outv;

    float* row = align + (size_t)b * T_SZ;
    #pragma unroll
    for (int s = 0; s < 4; ++s) {
        float4 vv = *(float4*)&row[(s * 256 + tid) * 4];
        vv.x = __expf(vv.x - M) * invZ;
        vv.y = __expf(vv.y - M) * invZ;
        vv.z = __expf(vv.z - M) * invZ;
        vv.w = __expf(vv.w - M) * invZ;
        *(float4*)&row[(s * 256 + tid) * 4] = vv;
    }
}

// ---------------------------------------------------------------------------
extern "C" void kernel_launch(void* const* d_in, const int* in_sizes, int n_in,
                              void* d_out, int out_size, void* d_ws, size_t ws_size,
                              hipStream_t stream) {
    const float* query  = (const float*)d_in[0];   // [32,1024]
    const float* memory = (const float*)d_in[1];   // [32,4096,512]
    const float* Wq     = (const float*)d_in[3];   // [1024,128]
    const float* Wm     = (const float*)d_in[4];   // [512,128]
    const float* v      = (const float*)d_in[5];   // [128]

    float* ctx_out   = (float*)d_out;                    // [32,512]
    float* align_out = (float*)d_out + B_SZ * E_SZ;      // [32,4096]

    char* ws = (char*)d_ws;
    float*          pq       = (float*)(ws + 0);               // 16 KB
    unsigned short* WmTh     = (unsigned short*)(ws + 16384);  // 128 KB
    unsigned short* WmTl     = (unsigned short*)(ws + 147456); // 128 KB
    float*          mZ       = (float*)(ws + 278528);          // 8 KB
    float*          ctx_part = (float*)(ws + 286720);          // 2 MB

    k_prep<<<160, 256, 0, stream>>>(query, Wq, Wm, pq, WmTh, WmTl);
    k_fused<<<dim3(NCH, B_SZ), 256, 0, stream>>>(memory, WmTh, WmTl, pq, v,
                                                 align_out, ctx_part, mZ);
    k_combine<<<B_SZ, 256, 0, stream>>>(ctx_part, mZ, ctx_out, align_out);
}